// Round 2
// baseline (560.278 us; speedup 1.0000x reference)
//
#include <hip/hip_runtime.h>

// AdaPool2D: 2x2 stride-2 window, blend of exp-softmax pooling and
// Dice-Sorensen-softmax pooling.
//   inputs: [B=32, W=224, H=224, C=64] fp32 (C contiguous innermost)
//   mask:   [1] fp32 blend scalar
//   out:    [B, 112, 112, 64] fp32
//
// Timed region is dominated by ~506 us of harness fillBuffer re-poison; the
// kernel itself runs in a cache-assisted regime (partial L3 residency of the
// input across iterations) well below the naive 82 us streaming floor.
// This version maximizes memory-level parallelism and L3 retention:
//   - one thread = four (b, wo, ho..ho+3) outputs x 4 channels
//   - 16 float4 loads in flight, 4 nontemporal stores
//   - REGULAR (cache-retaining) loads: input is re-read every timed iteration,
//     so evict-first 'nt' loads defeat the L3 residency that makes the kernel
//     fast. Stores stay nontemporal (output never re-read in the timed loop).
//   - grid divides exactly: no bounds check.

constexpr int Bn = 32;
constexpr int Wd = 224;
constexpr int Hd = 224;
constexpr int Cd = 64;
constexpr int Wo = 112;
constexpr int Ho = 112;
constexpr int Ho4 = Ho / 4;                        // 28 output-quads along ho
constexpr int HC = Hd * Cd;                        // 14336: W-row stride in floats
constexpr int TOTAL = Bn * Wo * Ho4 * (Cd / 4);    // 1,605,632 work items

using f32x4 = __attribute__((ext_vector_type(4))) float;

__device__ __forceinline__ f32x4 pool_win(f32x4 a4, f32x4 b4, f32x4 c4v, f32x4 d4,
                                          float m, float m1) {
    f32x4 r;
#pragma unroll
    for (int k = 0; k < 4; ++k) {
        float a = a4[k], bb = b4[k], cc = c4v[k], dd = d4[k];

        // exponential-maximum pooling: sum(p * softmax(p))
        float ea = __expf(a), eb = __expf(bb), ec = __expf(cc), ed = __expf(dd);
        float inv_se = __builtin_amdgcn_rcpf(ea + eb + ec + ed);
        float em = (a * ea + bb * eb + cc * ec + dd * ed) * inv_se;

        // eDSCW pooling: dsc = 2*avg*p / (avg^2 + p^2), softmax over window
        float avg  = 0.25f * (a + bb + cc + dd);
        float avg2 = avg * avg;
        float ta   = 2.0f * avg;
        float da = ta * a  * __builtin_amdgcn_rcpf(avg2 + a  * a);
        float db = ta * bb * __builtin_amdgcn_rcpf(avg2 + bb * bb);
        float dc = ta * cc * __builtin_amdgcn_rcpf(avg2 + cc * cc);
        float de = ta * dd * __builtin_amdgcn_rcpf(avg2 + dd * dd);
        float fa = __expf(da), fb = __expf(db), fc = __expf(dc), fd = __expf(de);
        float inv_sd = __builtin_amdgcn_rcpf(fa + fb + fc + fd);
        float dp = (a * fa + bb * fb + cc * fc + dd * fd) * inv_sd;

        r[k] = em * m + dp * m1;
    }
    return r;
}

__global__ __launch_bounds__(256)
void adapool2d_kernel(const float* __restrict__ in,
                      const float* __restrict__ mask,
                      float* __restrict__ out) {
    int i = blockIdx.x * 256 + threadIdx.x;   // grid divides TOTAL exactly

    const float m  = mask[0];          // uniform -> s_load
    const float m1 = 1.0f - m;

    // i = ((b*Wo + wo)*Ho4 + h4)*16 + c4g
    int c4g = i & 15;
    int t   = i >> 4;
    int h4  = t % Ho4;
    t       = t / Ho4;
    int wo  = t % Wo;
    int b   = t / Wo;
    int ho  = h4 * 4;                  // first of four output columns

    // Input base: row 2*wo, col 2*ho. This thread consumes input cols
    // 2ho..2ho+7 on rows 2wo and 2wo+1 (no overlap with neighbor threads).
    const float* p = in + (size_t)(b * Wd + 2 * wo) * HC + (2 * ho) * Cd + c4g * 4;
    const f32x4* q0 = reinterpret_cast<const f32x4*>(p);        // row 2wo
    const f32x4* q1 = reinterpret_cast<const f32x4*>(p + HC);   // row 2wo+1

    // f32x4 pointer stride of 16 == Cd floats == one input column.
    // 16 cache-retaining loads issued back-to-back (max MLP).
    f32x4 v0[8], v1[8];
#pragma unroll
    for (int c = 0; c < 8; ++c) v0[c] = q0[c * 16];
#pragma unroll
    for (int c = 0; c < 8; ++c) v1[c] = q1[c * 16];

    f32x4 r0 = pool_win(v0[0], v0[1], v1[0], v1[1], m, m1);   // (wo, ho)
    f32x4 r1 = pool_win(v0[2], v0[3], v1[2], v1[3], m, m1);   // (wo, ho+1)
    f32x4 r2 = pool_win(v0[4], v0[5], v1[4], v1[5], m, m1);   // (wo, ho+2)
    f32x4 r3 = pool_win(v0[6], v0[7], v1[6], v1[7], m, m1);   // (wo, ho+3)

    // Output float4 index: ((b*Wo + wo)*Ho + ho)*16 + c4g; next output +16.
    size_t o = ((size_t)(b * Wo + wo) * Ho + ho) * 16 + c4g;
    f32x4* op = reinterpret_cast<f32x4*>(out);
    __builtin_nontemporal_store(r0, op + o);
    __builtin_nontemporal_store(r1, op + o + 16);
    __builtin_nontemporal_store(r2, op + o + 32);
    __builtin_nontemporal_store(r3, op + o + 48);
}

extern "C" void kernel_launch(void* const* d_in, const int* in_sizes, int n_in,
                              void* d_out, int out_size, void* d_ws, size_t ws_size,
                              hipStream_t stream) {
    const float* in   = (const float*)d_in[0];
    const float* mask = (const float*)d_in[1];
    float* out        = (float*)d_out;

    constexpr int threads = 256;
    constexpr int blocks  = TOTAL / threads;   // 6272, exact
    adapool2d_kernel<<<blocks, threads, 0, stream>>>(in, mask, out);
}

// Round 3
// 531.809 us; speedup vs baseline: 1.0535x; 1.0535x over previous
//
#include <hip/hip_runtime.h>

// AdaPool2D: 2x2 stride-2 window, blend of exp-softmax pooling and
// Dice-Sorensen-softmax pooling.
//   inputs: [B=32, W=224, H=224, C=64] fp32 (C contiguous innermost)
//   mask:   [1] fp32 blend scalar
//   out:    [B, 112, 112, 64] fp32
//
// Timed region = ~506 us of harness fillBuffer re-poison (2 x 253 us, fixed)
// + ~28 us kernel. Kernel residual is TRANS-pipe-bound: R1 spent 896
// trans-cycles/wave (112 quarter-rate exp/rcp). This version cuts that to
// ~640 by:
//   - Montgomery batch inversion: 4 DSC-denominator rcps -> 1 rcp + 9 muls
//   - merged softmax normalizers: rcp(Se), rcp(Sd) -> rcp(Se*Sd) + 3 muls
//   - log2e folded into the DSC scale (native exp2 path)
// Structure is identical to the measured-best R1 kernel: 2 outputs/thread,
// 8 nontemporal float4 loads in flight, 2 nontemporal stores.

constexpr int Bn = 32;
constexpr int Wd = 224;
constexpr int Hd = 224;
constexpr int Cd = 64;
constexpr int Wo = 112;
constexpr int Ho = 112;
constexpr int Ho2 = Ho / 2;                        // 56 output-pairs along ho
constexpr int HC = Hd * Cd;                        // 14336: W-row stride in floats
constexpr int TOTAL = Bn * Wo * Ho2 * (Cd / 4);    // 3,211,264 work items

using f32x4 = __attribute__((ext_vector_type(4))) float;

#if __has_builtin(__builtin_amdgcn_exp2f)
#define EXP2(x) __builtin_amdgcn_exp2f(x)          // v_exp_f32 directly
#else
#define EXP2(x) __expf((x) * 0.69314718055994531f) // exp2(x) = e^(x ln2)
#endif

constexpr float LOG2E = 1.4426950408889634f;

__device__ __forceinline__ f32x4 pool_win(f32x4 a4, f32x4 b4, f32x4 c4v, f32x4 d4,
                                          float m, float m1) {
    f32x4 r;
#pragma unroll
    for (int k = 0; k < 4; ++k) {
        float a = a4[k], bb = b4[k], cc = c4v[k], dd = d4[k];

        // exponential-maximum pooling: sum(p * softmax(p))  [4 exp]
        float ea = EXP2(a  * LOG2E);
        float eb = EXP2(bb * LOG2E);
        float ec = EXP2(cc * LOG2E);
        float ed = EXP2(dd * LOG2E);
        float se   = (ea + eb) + (ec + ed);
        float nume = a * ea + bb * eb + cc * ec + dd * ed;

        // eDSCW pooling: dsc = 2*avg*p / (avg^2 + p^2), softmax over window
        float avg  = 0.25f * (a + bb + cc + dd);
        float avg2 = avg * avg;
        float na = avg2 + a  * a;
        float nb = avg2 + bb * bb;
        float nc = avg2 + cc * cc;
        float nd = avg2 + dd * dd;

        // Montgomery batch inversion: one rcp for all four denominators
        float mab   = na * nb;
        float mabc  = mab * nc;
        float mabcd = mabc * nd;
        float rinv  = __builtin_amdgcn_rcpf(mabcd);
        float ind   = rinv * mabc;      // 1/nd
        float rabc  = rinv * nd;        // 1/(na*nb*nc)
        float inc   = rabc * mab;       // 1/nc
        float rab   = rabc * nc;        // 1/(na*nb)
        float inb   = rab * na;         // 1/nb
        float ina   = rab * nb;         // 1/na

        // dsc_i * log2e directly: ta = 2*avg*log2e       [4 exp]
        float ta = (2.0f * LOG2E) * avg;
        float fa = EXP2(ta * a  * ina);
        float fb = EXP2(ta * bb * inb);
        float fc = EXP2(ta * cc * inc);
        float fd = EXP2(ta * dd * ind);
        float sd   = (fa + fb) + (fc + fd);
        float numd = a * fa + bb * fb + cc * fc + dd * fd;

        // merged softmax normalizers: one rcp serves both pools
        float invp = __builtin_amdgcn_rcpf(se * sd);
        float em = nume * sd * invp;
        float dp = numd * se * invp;

        r[k] = em * m + dp * m1;
    }
    return r;
}

__global__ __launch_bounds__(256)
void adapool2d_kernel(const float* __restrict__ in,
                      const float* __restrict__ mask,
                      float* __restrict__ out) {
    int i = blockIdx.x * 256 + threadIdx.x;   // grid divides TOTAL exactly

    const float m  = mask[0];          // uniform -> scalar load
    const float m1 = 1.0f - m;

    // i = ((b*Wo + wo)*Ho2 + h2)*16 + c4g
    int c4g = i & 15;
    int t   = i >> 4;
    int h2  = t % Ho2;
    t       = t / Ho2;
    int wo  = t % Wo;
    int b   = t / Wo;
    int ho  = h2 * 2;                  // first of the two output columns

    // Input base: row 2*wo, col 2*ho. This thread consumes input cols
    // 2ho..2ho+3 on rows 2wo and 2wo+1 (no overlap with neighbor threads).
    const float* p = in + (size_t)(b * Wd + 2 * wo) * HC + (2 * ho) * Cd + c4g * 4;
    const f32x4* q0 = reinterpret_cast<const f32x4*>(p);        // row 2wo
    const f32x4* q1 = reinterpret_cast<const f32x4*>(p + HC);   // row 2wo+1

    // f32x4 pointer stride of 16 == Cd floats == one input column.
    f32x4 v00 = __builtin_nontemporal_load(q0);        // (2wo  , 2ho  )
    f32x4 v01 = __builtin_nontemporal_load(q0 + 16);   // (2wo  , 2ho+1)
    f32x4 v02 = __builtin_nontemporal_load(q0 + 32);   // (2wo  , 2ho+2)
    f32x4 v03 = __builtin_nontemporal_load(q0 + 48);   // (2wo  , 2ho+3)
    f32x4 v10 = __builtin_nontemporal_load(q1);        // (2wo+1, 2ho  )
    f32x4 v11 = __builtin_nontemporal_load(q1 + 16);   // (2wo+1, 2ho+1)
    f32x4 v12 = __builtin_nontemporal_load(q1 + 32);   // (2wo+1, 2ho+2)
    f32x4 v13 = __builtin_nontemporal_load(q1 + 48);   // (2wo+1, 2ho+3)

    f32x4 r0 = pool_win(v00, v01, v10, v11, m, m1);    // output (wo, ho)
    f32x4 r1 = pool_win(v02, v03, v12, v13, m, m1);    // output (wo, ho+1)

    // Output float4 index: ((b*Wo + wo)*Ho + ho)*16 + c4g; second output +16.
    size_t o = ((size_t)(b * Wo + wo) * Ho + ho) * 16 + c4g;
    f32x4* op = reinterpret_cast<f32x4*>(out);
    __builtin_nontemporal_store(r0, op + o);
    __builtin_nontemporal_store(r1, op + o + 16);
}

extern "C" void kernel_launch(void* const* d_in, const int* in_sizes, int n_in,
                              void* d_out, int out_size, void* d_ws, size_t ws_size,
                              hipStream_t stream) {
    const float* in   = (const float*)d_in[0];
    const float* mask = (const float*)d_in[1];
    float* out        = (float*)d_out;

    constexpr int threads = 256;
    constexpr int blocks  = TOTAL / threads;   // 12544, exact
    adapool2d_kernel<<<blocks, threads, 0, stream>>>(in, mask, out);
}